// Round 23
// baseline (83.631 us; speedup 1.0000x reference)
//
#include <hip/hip_runtime.h>
#include <math.h>

// Problem constants (B=1)
#define T 2048
#define C 1024
#define H 16
#define HD 64
#define N3 (3*C)
#define NBLOCK 2048

typedef __attribute__((ext_vector_type(8))) short bf16x8;
typedef __attribute__((ext_vector_type(4))) float f32x4;

#define MFMA16(a, b, c) __builtin_amdgcn_mfma_f32_16x16x32_bf16((a), (b), (c), 0, 0, 0)

__device__ inline short f2bf(float f) {
    unsigned u; __builtin_memcpy(&u, &f, 4);
    unsigned r = (u + 0x7fffu + ((u >> 16) & 1u)) >> 16;
    return (short)r;
}
__device__ inline float bf2f(short s) {
    unsigned u = ((unsigned)(unsigned short)s) << 16;
    float f; __builtin_memcpy(&f, &u, 4);
    return f;
}

// async global->LDS, 16B per lane. lds base must be wave-uniform; HW adds lane*16.
__device__ inline void gload_lds16(const void* g, void* l) {
    __builtin_amdgcn_global_load_lds((const __attribute__((address_space(1))) unsigned int*)g,
                                     (__attribute__((address_space(3))) unsigned int*)l,
                                     16, 0, 0);
}

// ---------------- merged: (block 0) hist/scan prep + conv x + both weight transposes ----------------
// prep is block 0 so the serial 1-block scan dispatches FIRST and overlaps the rest.
__global__ __launch_bounds__(256) void pre_kernel(const float* __restrict__ x,
                                                  const float* __restrict__ w_attn,
                                                  const float* __restrict__ w_proj,
                                                  const int* __restrict__ tok,
                                                  const float* __restrict__ padmask,
                                                  short* __restrict__ xb,
                                                  short* __restrict__ wabT,
                                                  short* __restrict__ wpbT,
                                                  float* __restrict__ partial,
                                                  float* __restrict__ pm_tok) {
    int bid = blockIdx.x;
    int tid = threadIdx.x;
    if (bid == 0) {
        // fused histogram + scan + pm gather (single block)
        __shared__ float cntS[NBLOCK];
        __shared__ float sums[256];
        #pragma unroll
        for (int j = 0; j < 8; ++j) cntS[tid * 8 + j] = 0.0f;
        __syncthreads();
        int tk[8];
        #pragma unroll
        for (int j = 0; j < 8; ++j) {
            tk[j] = tok[tid * 8 + j];
            atomicAdd(&cntS[tk[j]], 1.0f);
        }
        __syncthreads();
        float vals[8];
        float s = 0.0f;
        #pragma unroll
        for (int j = 0; j < 8; ++j) {
            s += 1.0f / (cntS[tk[j]] + 1e-10f);
            vals[j] = s;
            pm_tok[tid * 8 + j] = padmask[tk[j]];
        }
        sums[tid] = s;
        __syncthreads();
        for (int off = 1; off < 256; off <<= 1) {
            float v = (tid >= off) ? sums[tid - off] : 0.0f;
            __syncthreads();
            sums[tid] += v;
            __syncthreads();
        }
        float offset = (tid > 0) ? sums[tid - 1] : 0.0f;
        #pragma unroll
        for (int j = 0; j < 8; ++j) partial[tid * 8 + j] = offset + vals[j];
        return;
    }
    if (bid < 2049) {
        int i = (bid - 1) * 1024 + tid * 4;
        float4 v = *(const float4*)(x + i);
        short4 o;
        o.x = f2bf(v.x); o.y = f2bf(v.y); o.z = f2bf(v.z); o.w = f2bf(v.w);
        *(short4*)(xb + i) = o;
        return;
    }
    __shared__ float S[64][65];
    const float* in; short* out; int Kd, Nd, bx, by;
    if (bid < 2817) {
        int b = bid - 2049;              // (48, 16)
        bx = b % 48; by = b / 48;
        in = w_attn; out = wabT; Kd = C; Nd = N3;
    } else {
        int b = bid - 2817;              // (16, 16)
        bx = b % 16; by = b / 16;
        in = w_proj; out = wpbT; Kd = C; Nd = C;
    }
    int n0 = bx * 64, k0 = by * 64;
    #pragma unroll
    for (int i = 0; i < 16; ++i) {
        int lin = tid + i * 256;
        int r = lin >> 6, c = lin & 63;
        S[r][c] = in[(size_t)(k0 + r) * Nd + n0 + c];
    }
    __syncthreads();
    #pragma unroll
    for (int i = 0; i < 16; ++i) {
        int lin = tid + i * 256;
        int rn = lin >> 6, ck = lin & 63;
        out[(size_t)(n0 + rn) * Kd + k0 + ck] = f2bf(S[ck][rn]);
    }
}

// ---------------- bf16 GEMM (B^T): 64x128 tile, BK=64, TWO-PHASE pipeline, XCD swizzle ----------------
// EPI=0: plain out (+bias). EPI=1: fused QKV epilogue (rope q/k + fixups; v -> scaled vbT).
// EPI=2: proj GEMM with FUSED COMBINE: m-tiles >= 1024 reg-stage A from bf16 Opart slabs
//        (add kh0+kh1, scale by 1/l from Lpart), m-tiles < 1024 use gload_lds from yb.
//        Param aliases for EPI=2: partial -> Lpart, vbT -> Opart.
template <int OUT_BF16, int EPI>
__global__ __launch_bounds__(256) void gemm_bt64(const short* __restrict__ A,
                                                 const short* __restrict__ Bt,
                                                 const float* __restrict__ bias,
                                                 void* __restrict__ Cout,
                                                 int M, int N, int K,
                                                 const float* __restrict__ partial,
                                                 const float* __restrict__ cumsc,
                                                 const float* __restrict__ pm_tok,
                                                 short* __restrict__ vbT) {
    __shared__ alignas(16) short As[2][2][64 * 32];   // [phase][half]
    __shared__ alignas(16) short Bs[2][2][128 * 32];
    __shared__ float linvS[EPI == 2 ? 16 : 1][64];    // [head][q-local] (EPI=2 only)
    int tid = threadIdx.x;
    // bijective XCD swizzle: XCD x processes a contiguous raster chunk
    int nwg = gridDim.x * gridDim.y;
    int bidl = blockIdx.y * gridDim.x + blockIdx.x;
    int swz = (bidl & 7) * (nwg >> 3) + (bidl >> 3);
    int m0 = (swz / gridDim.x) * 64, n0 = (swz % gridDim.x) * 128;
    int w = tid >> 6, l = tid & 63;
    int wm = (w >> 1) * 32, wn = (w & 1) * 64;
    int lq = l & 15, g = l >> 4;
    int prow = l >> 2, pcol = (l & 3) * 8;    // lane slot within a 1KB chunk (16 rows x 32 cols)
    f32x4 acc[2][4] = {};

    bool fuseA = (EPI == 2) && (m0 >= 1024);
    if (fuseA) {
        int qt16 = (m0 >> 6) - 16;            // 0..15
        #pragma unroll
        for (int e = 0; e < 4; ++e) {
            int idx = tid * 4 + e;            // 0..1023
            int hh = idx >> 6, q = idx & 63;
            int s = hh * 16 + qt16;
            linvS[hh][q] = 1.0f / (partial[s * 64 + q] + partial[(256 + s) * 64 + q]);
        }
    }
    if (EPI == 2) __syncthreads();            // linvS visible before first stage

    auto stage = [&](int ph, int k0) {
        #pragma unroll
        for (int hf = 0; hf < 2; ++hf) {
            int kk = k0 + hf * 32;
            int rowA = w * 16 + prow;
            if (fuseA) {
                // A[m][k] = (O0 + O1) * linv ; slab = (h, qt) ; q-local = rowA
                int hh = k0 >> 6;             // hf*32+pcol < 64: same head
                int s = hh * 16 + ((m0 >> 6) - 16);
                int dcol = hf * 32 + pcol;
                size_t off = (size_t)s * 4096 + rowA * 64 + dcol;
                bf16x8 a = *(const bf16x8*)(vbT + off);
                bf16x8 b2 = *(const bf16x8*)(vbT + (size_t)256 * 4096 + off);
                float li = linvS[hh][rowA];
                bf16x8 o;
                #pragma unroll
                for (int i = 0; i < 8; ++i) o[i] = f2bf((bf2f(a[i]) + bf2f(b2[i])) * li);
                *(bf16x8*)(As[ph][hf] + rowA * 32 + pcol) = o;
            } else {
                gload_lds16(A + (size_t)(m0 + rowA) * K + kk + pcol, As[ph][hf] + w * 512);
            }
            #pragma unroll
            for (int i = 0; i < 2; ++i) {
                int c = w * 2 + i;
                int row = c * 16 + prow;
                gload_lds16(Bt + (size_t)(n0 + row) * K + kk + pcol, Bs[ph][hf] + c * 512);
            }
        }
    };

    int NK = K / 64;
    stage(0, 0);
    __syncthreads();
    for (int t = 0; t < NK; ++t) {
        int ph = t & 1;
        if (t + 1 < NK) stage(ph ^ 1, (t + 1) * 64);   // prefetch flies under compute
        #pragma unroll
        for (int hf = 0; hf < 2; ++hf) {
            bf16x8 af[2], bfr[4];
            #pragma unroll
            for (int f = 0; f < 2; ++f)
                af[f] = *(const bf16x8*)(As[ph][hf] + (wm + f * 16 + lq) * 32 + g * 8);
            #pragma unroll
            for (int j = 0; j < 4; ++j)
                bfr[j] = *(const bf16x8*)(Bs[ph][hf] + (wn + j * 16 + lq) * 32 + g * 8);
            #pragma unroll
            for (int fi = 0; fi < 2; ++fi)
                #pragma unroll
                for (int fj = 0; fj < 4; ++fj)
                    acc[fi][fj] = MFMA16(af[fi], bfr[fj], acc[fi][fj]);
        }
        __syncthreads();   // implicit vmcnt(0) lands the prefetch; WAR safe (1-barrier distance)
    }

    if (EPI != 1) {
        #pragma unroll
        for (int fi = 0; fi < 2; ++fi)
            #pragma unroll
            for (int fj = 0; fj < 4; ++fj)
                #pragma unroll
                for (int r = 0; r < 4; ++r) {
                    int m = m0 + wm + fi * 16 + g * 4 + r;
                    int n = n0 + wn + fj * 16 + lq;
                    float v = acc[fi][fj][r] + bias[n];
                    if (OUT_BF16) ((short*)Cout)[(size_t)m * N + n] = f2bf(v);
                    else          ((float*)Cout)[(size_t)m * N + n] = v;
                }
    } else {
        // wave strip = one head (64 cols) at cb; 128-col tiles never straddle sections.
        short* Cb = (short*)Cout;              // qkvb
        int cb = n0 + wn;
        int section = cb >> 10;                // 0 q, 1 k, 2 v
        float b0 = bias[cb + lq],      b1 = bias[cb + 16 + lq];
        float b2 = bias[cb + 32 + lq], b3 = bias[cb + 48 + lq];
        if (section < 2) {
            bool isQ = (section == 0);
            float inv0 = exp2f(-(float)lq * (13.287712379549449f / 32.0f));         // j = lq
            float inv1 = exp2f(-(float)(lq + 16) * (13.287712379549449f / 32.0f));  // j = lq+16
            #pragma unroll
            for (int fi = 0; fi < 2; ++fi)
                #pragma unroll
                for (int r = 0; r < 4; ++r) {
                    int trow = m0 + wm + fi * 16 + g * 4 + r;
                    float pt = partial[trow];
                    float sn0, cs0, sn1, cs1;
                    __sincosf(pt * inv0, &sn0, &cs0);
                    __sincosf(pt * inv1, &sn1, &cs1);
                    float a0 = acc[fi][0][r] + b0;
                    float a1 = acc[fi][1][r] + b1;
                    float a2 = acc[fi][2][r] + b2;
                    float a3 = acc[fi][3][r] + b3;
                    float lo0 = a0 * cs0 - a2 * sn0;
                    float hi0 = a2 * cs0 + a0 * sn0;
                    float lo1 = a1 * cs1 - a3 * sn1;
                    float hi1 = a3 * cs1 + a1 * sn1;
                    if (lq == 15) {   // d == 63 fixups (padding folded in)
                        float pm = pm_tok[trow];
                        hi1 = isQ ? ((pm != 0.0f) ? 1.0f : 0.0f)
                                  : ((pm != 0.0f) ? cumsc[trow] : -1e20f);
                    }
                    size_t base = (size_t)trow * N3 + cb;
                    Cb[base + lq]      = f2bf(lo0);
                    Cb[base + 16 + lq] = f2bf(lo1);
                    Cb[base + 32 + lq] = f2bf(hi0);
                    Cb[base + 48 + lq] = f2bf(hi1);
                }
        } else {
            // V: write only transposed + exp(cum)-scaled vbT[h*64+d][t], 8B stores
            int h = (cb - 2 * C) >> 6;
            #pragma unroll
            for (int fi = 0; fi < 2; ++fi) {
                int tb = m0 + wm + fi * 16 + g * 4;
                float ef[4];
                #pragma unroll
                for (int r = 0; r < 4; ++r) ef[r] = __expf(cumsc[tb + r]);
                #pragma unroll
                for (int fj = 0; fj < 4; ++fj) {
                    int d = fj * 16 + lq;
                    float bv = (fj == 0) ? b0 : (fj == 1) ? b1 : (fj == 2) ? b2 : b3;
                    short4 o;
                    o.x = f2bf((acc[fi][fj][0] + bv) * ef[0]);
                    o.y = f2bf((acc[fi][fj][1] + bv) * ef[1]);
                    o.z = f2bf((acc[fi][fj][2] + bv) * ef[2]);
                    o.w = f2bf((acc[fi][fj][3] + bv) * ef[3]);
                    *(short4*)(vbT + (size_t)(h * 64 + d) * T + tb) = o;
                }
            }
        }
    }
}

// ---------------- MFMA flash attention: cross-block K-split for long chains ----------------
// 768 independent blocks (3/CU co-resident, 12 waves/CU; per-CU tile load = 33 uniform):
//   b in [0,256):   kh0 of (h, qt=16+(b>>4)): k-tiles [0,17)      -> partial (bf16)
//   b in [256,512): kh1 of (h, qt=31-((b-256)>>4)): k-tiles [17,qt] -> partial (may be empty)
//   b in [512,768): short (h, qt=(b-512)>>4): k-tiles [0,qt]      -> direct yb
// Streaming softmax => partials are purely additive (bf16 accO + f32 row-sums); no m/l merge.
__global__ __launch_bounds__(256) void attn_flash(const short* __restrict__ qkvb,
                                                  const short* __restrict__ vbT,
                                                  short* __restrict__ yb,
                                                  short* __restrict__ Opart,
                                                  float* __restrict__ Lpart) {
    __shared__ alignas(16) short Kt[2][64 * 64];      // [k][d], XOR-swizzled rows
    __shared__ alignas(16) short Vt[2][64 * 64];      // [d][k], XOR-swizzled rows
    __shared__ alignas(16) short Ps[4][16][72];       // wave-private P[q][k]

    int b = blockIdx.x;
    int h, qt, t0, t1, mode;                          // mode: 0 direct, 1 kh0 partial, 2 kh1 partial
    if (b < 256)      { h = b & 15; qt = 16 + (b >> 4); t0 = 0;  t1 = 16; mode = 1; }
    else if (b < 512) { int c = b - 256; h = c & 15; qt = 31 - (c >> 4); t0 = 17; t1 = qt; mode = 2; }
    else              { int c = b - 512; h = c & 15; qt = c >> 4; t0 = 0; t1 = qt; mode = 0; }
    int nt = t1 - t0 + 1;                             // may be 0 (mode 2, qt==16)

    int tid = threadIdx.x;
    int w = tid >> 6, l = tid & 63;
    int lq = l & 15, g = l >> 4;
    int qrl = w * 16 + lq;                            // q-row local to the 64-row q-tile
    int qrow = qt * 64 + qrl;

    const short* qbase = qkvb + (size_t)qrow * N3 + h * 64;
    bf16x8 qf0 = *(const bf16x8*)(qbase + g * 8);
    bf16x8 qf1 = *(const bf16x8*)(qbase + 32 + g * 8);

    f32x4 accO[4] = {};    // [f]: d = 16f + lq ; q-rows = 4g + r
    float lsum = 0.0f;

    // staging geometry: thread covers rows srow, srow+32; 8 cols at scol
    int srow = tid >> 3, scol = (tid & 7) * 8;
    const short* kgb = qkvb + C + h * 64 + scol;
    const short* vgb = vbT + (size_t)(h * 64) * T + scol;
    int wb0 = srow * 128 + ((scol * 2) ^ ((srow & 7) << 4));
    int wb1 = (srow + 32) * 128 + ((scol * 2) ^ ((srow & 7) << 4));

    uint4 kr0, kr1, vr0, vr1;
    auto stageRegs = [&](int tile) {
        int kb = tile * 64;
        kr0 = *(const uint4*)(kgb + (size_t)(kb + srow) * N3);
        kr1 = *(const uint4*)(kgb + (size_t)(kb + srow + 32) * N3);
        vr0 = *(const uint4*)(vgb + (size_t)srow * T + kb);
        vr1 = *(const uint4*)(vgb + (size_t)(srow + 32) * T + kb);
    };
    auto writeLds = [&](int buf) {
        *(uint4*)((char*)Kt[buf] + wb0) = kr0;
        *(uint4*)((char*)Kt[buf] + wb1) = kr1;
        *(uint4*)((char*)Vt[buf] + wb0) = vr0;
        *(uint4*)((char*)Vt[buf] + wb1) = vr1;
    };

    auto do_tile = [&](int buf, bool masked) {
        const char* Kc = (const char*)Kt[buf];
        const char* Vc = (const char*)Vt[buf];
        // ---- S^T = K · Q^T ----
        f32x4 s[4] = {};
        __builtin_amdgcn_s_setprio(1);
        #pragma unroll
        for (int f = 0; f < 4; ++f) {
            int row = f * 16 + lq;
            const char* kr_ = Kc + row * 128;
            int sw = (row & 7) << 4;
            bf16x8 a0 = *(const bf16x8*)(kr_ + ((g * 16) ^ sw));
            bf16x8 a1 = *(const bf16x8*)(kr_ + ((64 + g * 16) ^ sw));
            s[f] = MFMA16(a0, qf0, s[f]);
            s[f] = MFMA16(a1, qf1, s[f]);
        }
        __builtin_amdgcn_s_setprio(0);
        // ---- streaming softmax: p = exp(s/8), no max-tracking ----
        float p[16];
        #pragma unroll
        for (int f = 0; f < 4; ++f)
            #pragma unroll
            for (int r = 0; r < 4; ++r) {
                float sv = s[f][r] * 0.125f;
                if (masked) {
                    int kl = f * 16 + g * 4 + r;
                    sv = (kl > qrl) ? -INFINITY : sv;
                }
                float pv = __expf(sv);
                p[f * 4 + r] = pv;
                lsum += pv;
            }
        // ---- pack P to bf16, transpose through wave-private LDS ----
        #pragma unroll
        for (int f = 0; f < 4; ++f) {
            unsigned u0, u1;
            asm("v_cvt_pk_bf16_f32 %0, %1, %2" : "=v"(u0) : "v"(p[f * 4 + 0]), "v"(p[f * 4 + 1]));
            asm("v_cvt_pk_bf16_f32 %0, %1, %2" : "=v"(u1) : "v"(p[f * 4 + 2]), "v"(p[f * 4 + 3]));
            uint2 uu; uu.x = u0; uu.y = u1;
            *(uint2*)&Ps[w][lq][f * 16 + g * 4] = uu;
        }
        // ---- O += P · V ----
        __builtin_amdgcn_s_setprio(1);
        #pragma unroll
        for (int kh = 0; kh < 2; ++kh) {
            bf16x8 pa = *(const bf16x8*)&Ps[w][lq][kh * 32 + g * 8];
            #pragma unroll
            for (int f = 0; f < 4; ++f) {
                int vrow = f * 16 + lq;
                const char* vr_ = Vc + vrow * 128;
                bf16x8 vb = *(const bf16x8*)(vr_ + (((kh * 32 + g * 8) * 2) ^ ((vrow & 7) << 4)));
                accO[f] = MFMA16(pa, vb, accO[f]);
            }
        }
        __builtin_amdgcn_s_setprio(0);
    };

    // prologue: stage first tile (if any work)
    if (nt > 0) { stageRegs(t0); writeLds(0); }
    __syncthreads();

    for (int j = 0; j < nt; ++j) {
        int t = t0 + j;
        bool pf = (j + 1 < nt);
        if (pf) stageRegs(t + 1);
        do_tile(j & 1, t == qt);
        if (pf) writeLds((j & 1) ^ 1);
        __syncthreads();
    }

    // row-sum reduce across the 4 g-groups (result replicated per lane)
    lsum += __shfl_xor(lsum, 16);
    lsum += __shfl_xor(lsum, 32);

    if (mode == 0) {
        float linv_own = 1.0f / lsum;
        float li[4];
        #pragma unroll
        for (int r = 0; r < 4; ++r) li[r] = __shfl(linv_own, g * 4 + r);
        #pragma unroll
        for (int f = 0; f < 4; ++f)
            #pragma unroll
            for (int r = 0; r < 4; ++r) {
                int trow = qt * 64 + w * 16 + g * 4 + r;
                yb[(size_t)trow * C + h * 64 + f * 16 + lq] = f2bf(accO[f][r] * li[r]);
            }
    } else {
        int kh = mode - 1;
        int slab = h * 16 + (qt - 16);
        short* Ob = Opart + ((size_t)kh * 256 + slab) * 4096;
        #pragma unroll
        for (int f = 0; f < 4; ++f)
            #pragma unroll
            for (int r = 0; r < 4; ++r)
                Ob[(w * 16 + g * 4 + r) * 64 + f * 16 + lq] = f2bf(accO[f][r]);
        if (g == 0) Lpart[((size_t)kh * 256 + slab) * 64 + w * 16 + lq] = lsum;
    }
}

extern "C" void kernel_launch(void* const* d_in, const int* in_sizes, int n_in,
                              void* d_out, int out_size, void* d_ws, size_t ws_size,
                              hipStream_t stream) {
    const float* x       = (const float*)d_in[0];
    const float* cumsc   = (const float*)d_in[1];
    const float* padmask = (const float*)d_in[2];
    const int*   tok     = (const int*)d_in[3];
    const float* w_attn  = (const float*)d_in[4];
    const float* b_attn  = (const float*)d_in[5];
    const float* w_proj  = (const float*)d_in[6];
    const float* b_proj  = (const float*)d_in[7];
    float* out = (float*)d_out;

    float* part   = (float*)d_ws;                 // 2048
    float* pm_tok = part + 2048;                  // 2048
    float* Lpart  = pm_tok + 2048;                // 2*256*64
    short* Opart  = (short*)(Lpart + 2 * 256 * 64);  // 2*256*4096 bf16 (4MB)
    short* xb     = Opart + (size_t)2 * 256 * 4096;  // T*C
    short* wabT   = xb + (size_t)T * C;           // 3C*C
    short* wpbT   = wabT + (size_t)N3 * C;        // C*C
    short* qkvb   = wpbT + (size_t)C * C;         // T*3C (v-section unused)
    short* vbT    = qkvb + (size_t)T * N3;        // C*T
    short* yb     = vbT + (size_t)C * T;          // T*C (rows >=1024 never written; proj reads Opart)

    pre_kernel<<<3073, 256, 0, stream>>>(x, w_attn, w_proj, tok, padmask,
                                         xb, wabT, wpbT, part, pm_tok);
    gemm_bt64<1, 1><<<dim3(N3 / 128, T / 64), 256, 0, stream>>>(
        xb, wabT, b_attn, qkvb, T, N3, C, part, cumsc, pm_tok, vbT);
    attn_flash<<<768, 256, 0, stream>>>(qkvb, vbT, yb, Opart, Lpart);
    // proj with fused combine: partial -> Lpart, vbT -> Opart
    gemm_bt64<0, 2><<<dim3(C / 128, T / 64), 256, 0, stream>>>(
        yb, wpbT, b_proj, out, T, C, C, Lpart, nullptr, nullptr, Opart);
}

// Round 24
// 76.964 us; speedup vs baseline: 1.0866x; 1.0866x over previous
//
#include <hip/hip_runtime.h>
#include <math.h>

// Problem constants (B=1)
#define T 2048
#define C 1024
#define H 16
#define HD 64
#define N3 (3*C)
#define NBLOCK 2048

typedef __attribute__((ext_vector_type(8))) short bf16x8;
typedef __attribute__((ext_vector_type(4))) float f32x4;

#define MFMA16(a, b, c) __builtin_amdgcn_mfma_f32_16x16x32_bf16((a), (b), (c), 0, 0, 0)

__device__ inline short f2bf(float f) {
    unsigned u; __builtin_memcpy(&u, &f, 4);
    unsigned r = (u + 0x7fffu + ((u >> 16) & 1u)) >> 16;
    return (short)r;
}
__device__ inline float bf2f(short s) {
    unsigned u = ((unsigned)(unsigned short)s) << 16;
    float f; __builtin_memcpy(&f, &u, 4);
    return f;
}

// async global->LDS, 16B per lane. lds base must be wave-uniform; HW adds lane*16.
__device__ inline void gload_lds16(const void* g, void* l) {
    __builtin_amdgcn_global_load_lds((const __attribute__((address_space(1))) unsigned int*)g,
                                     (__attribute__((address_space(3))) unsigned int*)l,
                                     16, 0, 0);
}

// ---------------- merged: (block 0) hist/scan prep + conv x + both weight transposes ----------------
// prep is block 0 so the serial 1-block scan dispatches FIRST and overlaps the rest.
__global__ __launch_bounds__(256) void pre_kernel(const float* __restrict__ x,
                                                  const float* __restrict__ w_attn,
                                                  const float* __restrict__ w_proj,
                                                  const int* __restrict__ tok,
                                                  const float* __restrict__ padmask,
                                                  short* __restrict__ xb,
                                                  short* __restrict__ wabT,
                                                  short* __restrict__ wpbT,
                                                  float* __restrict__ partial,
                                                  float* __restrict__ pm_tok) {
    int bid = blockIdx.x;
    int tid = threadIdx.x;
    if (bid == 0) {
        // fused histogram + scan + pm gather (single block)
        __shared__ float cntS[NBLOCK];
        __shared__ float sums[256];
        #pragma unroll
        for (int j = 0; j < 8; ++j) cntS[tid * 8 + j] = 0.0f;
        __syncthreads();
        int tk[8];
        #pragma unroll
        for (int j = 0; j < 8; ++j) {
            tk[j] = tok[tid * 8 + j];
            atomicAdd(&cntS[tk[j]], 1.0f);
        }
        __syncthreads();
        float vals[8];
        float s = 0.0f;
        #pragma unroll
        for (int j = 0; j < 8; ++j) {
            s += 1.0f / (cntS[tk[j]] + 1e-10f);
            vals[j] = s;
            pm_tok[tid * 8 + j] = padmask[tk[j]];
        }
        sums[tid] = s;
        __syncthreads();
        for (int off = 1; off < 256; off <<= 1) {
            float v = (tid >= off) ? sums[tid - off] : 0.0f;
            __syncthreads();
            sums[tid] += v;
            __syncthreads();
        }
        float offset = (tid > 0) ? sums[tid - 1] : 0.0f;
        #pragma unroll
        for (int j = 0; j < 8; ++j) partial[tid * 8 + j] = offset + vals[j];
        return;
    }
    if (bid < 2049) {
        int i = (bid - 1) * 1024 + tid * 4;
        float4 v = *(const float4*)(x + i);
        short4 o;
        o.x = f2bf(v.x); o.y = f2bf(v.y); o.z = f2bf(v.z); o.w = f2bf(v.w);
        *(short4*)(xb + i) = o;
        return;
    }
    __shared__ float S[64][65];
    const float* in; short* out; int Kd, Nd, bx, by;
    if (bid < 2817) {
        int b = bid - 2049;              // (48, 16)
        bx = b % 48; by = b / 48;
        in = w_attn; out = wabT; Kd = C; Nd = N3;
    } else {
        int b = bid - 2817;              // (16, 16)
        bx = b % 16; by = b / 16;
        in = w_proj; out = wpbT; Kd = C; Nd = C;
    }
    int n0 = bx * 64, k0 = by * 64;
    #pragma unroll
    for (int i = 0; i < 16; ++i) {
        int lin = tid + i * 256;
        int r = lin >> 6, c = lin & 63;
        S[r][c] = in[(size_t)(k0 + r) * Nd + n0 + c];
    }
    __syncthreads();
    #pragma unroll
    for (int i = 0; i < 16; ++i) {
        int lin = tid + i * 256;
        int rn = lin >> 6, ck = lin & 63;
        out[(size_t)(n0 + rn) * Kd + k0 + ck] = f2bf(S[ck][rn]);
    }
}

// ---------------- bf16 GEMM (B^T): 64x128 tile, BK=64, TWO-PHASE pipeline, XCD swizzle ----------------
template <int OUT_BF16, int EPI>
__global__ __launch_bounds__(256) void gemm_bt64(const short* __restrict__ A,
                                                 const short* __restrict__ Bt,
                                                 const float* __restrict__ bias,
                                                 void* __restrict__ Cout,
                                                 int M, int N, int K,
                                                 const float* __restrict__ partial,
                                                 const float* __restrict__ cumsc,
                                                 const float* __restrict__ pm_tok,
                                                 short* __restrict__ vbT) {
    __shared__ alignas(16) short As[2][2][64 * 32];   // [phase][half]
    __shared__ alignas(16) short Bs[2][2][128 * 32];
    int tid = threadIdx.x;
    // bijective XCD swizzle: XCD x processes a contiguous raster chunk
    int nwg = gridDim.x * gridDim.y;
    int bidl = blockIdx.y * gridDim.x + blockIdx.x;
    int swz = (bidl & 7) * (nwg >> 3) + (bidl >> 3);
    int m0 = (swz / gridDim.x) * 64, n0 = (swz % gridDim.x) * 128;
    int w = tid >> 6, l = tid & 63;
    int wm = (w >> 1) * 32, wn = (w & 1) * 64;
    int lq = l & 15, g = l >> 4;
    int prow = l >> 2, pcol = (l & 3) * 8;    // lane slot within a 1KB chunk (16 rows x 32 cols)
    f32x4 acc[2][4] = {};

    auto stage = [&](int ph, int k0) {
        #pragma unroll
        for (int hf = 0; hf < 2; ++hf) {
            int kk = k0 + hf * 32;
            int rowA = w * 16 + prow;
            gload_lds16(A + (size_t)(m0 + rowA) * K + kk + pcol, As[ph][hf] + w * 512);
            #pragma unroll
            for (int i = 0; i < 2; ++i) {
                int c = w * 2 + i;
                int row = c * 16 + prow;
                gload_lds16(Bt + (size_t)(n0 + row) * K + kk + pcol, Bs[ph][hf] + c * 512);
            }
        }
    };

    int NK = K / 64;
    stage(0, 0);
    __syncthreads();
    for (int t = 0; t < NK; ++t) {
        int ph = t & 1;
        if (t + 1 < NK) stage(ph ^ 1, (t + 1) * 64);   // prefetch flies under compute
        #pragma unroll
        for (int hf = 0; hf < 2; ++hf) {
            bf16x8 af[2], bfr[4];
            #pragma unroll
            for (int f = 0; f < 2; ++f)
                af[f] = *(const bf16x8*)(As[ph][hf] + (wm + f * 16 + lq) * 32 + g * 8);
            #pragma unroll
            for (int j = 0; j < 4; ++j)
                bfr[j] = *(const bf16x8*)(Bs[ph][hf] + (wn + j * 16 + lq) * 32 + g * 8);
            #pragma unroll
            for (int fi = 0; fi < 2; ++fi)
                #pragma unroll
                for (int fj = 0; fj < 4; ++fj)
                    acc[fi][fj] = MFMA16(af[fi], bfr[fj], acc[fi][fj]);
        }
        __syncthreads();   // implicit vmcnt(0) lands the prefetch; WAR safe (1-barrier distance)
    }

    if (EPI == 0) {
        #pragma unroll
        for (int fi = 0; fi < 2; ++fi)
            #pragma unroll
            for (int fj = 0; fj < 4; ++fj)
                #pragma unroll
                for (int r = 0; r < 4; ++r) {
                    int m = m0 + wm + fi * 16 + g * 4 + r;
                    int n = n0 + wn + fj * 16 + lq;
                    float v = acc[fi][fj][r] + bias[n];
                    if (OUT_BF16) ((short*)Cout)[(size_t)m * N + n] = f2bf(v);
                    else          ((float*)Cout)[(size_t)m * N + n] = v;
                }
    } else {
        // wave strip = one head (64 cols) at cb; 128-col tiles never straddle sections.
        short* Cb = (short*)Cout;              // qkvb
        int cb = n0 + wn;
        int section = cb >> 10;                // 0 q, 1 k, 2 v
        float b0 = bias[cb + lq],      b1 = bias[cb + 16 + lq];
        float b2 = bias[cb + 32 + lq], b3 = bias[cb + 48 + lq];
        if (section < 2) {
            bool isQ = (section == 0);
            float inv0 = exp2f(-(float)lq * (13.287712379549449f / 32.0f));         // j = lq
            float inv1 = exp2f(-(float)(lq + 16) * (13.287712379549449f / 32.0f));  // j = lq+16
            #pragma unroll
            for (int fi = 0; fi < 2; ++fi)
                #pragma unroll
                for (int r = 0; r < 4; ++r) {
                    int trow = m0 + wm + fi * 16 + g * 4 + r;
                    float pt = partial[trow];
                    float sn0, cs0, sn1, cs1;
                    __sincosf(pt * inv0, &sn0, &cs0);
                    __sincosf(pt * inv1, &sn1, &cs1);
                    float a0 = acc[fi][0][r] + b0;
                    float a1 = acc[fi][1][r] + b1;
                    float a2 = acc[fi][2][r] + b2;
                    float a3 = acc[fi][3][r] + b3;
                    float lo0 = a0 * cs0 - a2 * sn0;
                    float hi0 = a2 * cs0 + a0 * sn0;
                    float lo1 = a1 * cs1 - a3 * sn1;
                    float hi1 = a3 * cs1 + a1 * sn1;
                    if (lq == 15) {   // d == 63 fixups (padding folded in)
                        float pm = pm_tok[trow];
                        hi1 = isQ ? ((pm != 0.0f) ? 1.0f : 0.0f)
                                  : ((pm != 0.0f) ? cumsc[trow] : -1e20f);
                    }
                    size_t base = (size_t)trow * N3 + cb;
                    Cb[base + lq]      = f2bf(lo0);
                    Cb[base + 16 + lq] = f2bf(lo1);
                    Cb[base + 32 + lq] = f2bf(hi0);
                    Cb[base + 48 + lq] = f2bf(hi1);
                }
        } else {
            // V: write only transposed + exp(cum)-scaled vbT[h*64+d][t], 8B stores
            int h = (cb - 2 * C) >> 6;
            #pragma unroll
            for (int fi = 0; fi < 2; ++fi) {
                int tb = m0 + wm + fi * 16 + g * 4;
                float ef[4];
                #pragma unroll
                for (int r = 0; r < 4; ++r) ef[r] = __expf(cumsc[tb + r]);
                #pragma unroll
                for (int fj = 0; fj < 4; ++fj) {
                    int d = fj * 16 + lq;
                    float bv = (fj == 0) ? b0 : (fj == 1) ? b1 : (fj == 2) ? b2 : b3;
                    short4 o;
                    o.x = f2bf((acc[fi][fj][0] + bv) * ef[0]);
                    o.y = f2bf((acc[fi][fj][1] + bv) * ef[1]);
                    o.z = f2bf((acc[fi][fj][2] + bv) * ef[2]);
                    o.w = f2bf((acc[fi][fj][3] + bv) * ef[3]);
                    *(short4*)(vbT + (size_t)(h * 64 + d) * T + tb) = o;
                }
            }
        }
    }
}

// ---------------- MFMA flash attention: cross-block K-split for long chains ----------------
// 768 independent blocks (3/CU co-resident, 12 waves/CU; per-CU tile load = 33 uniform):
//   b in [0,256):   kh0 of (h, qt=16+(b>>4)): k-tiles [0,17)      -> partial (bf16)
//   b in [256,512): kh1 of (h, qt=31-((b-256)>>4)): k-tiles [17,qt] -> partial (may be empty)
//   b in [512,768): short (h, qt=(b-512)>>4): k-tiles [0,qt]      -> direct yb
// Streaming softmax => partials are purely additive (bf16 accO + f32 row-sums); no m/l merge.
__global__ __launch_bounds__(256) void attn_flash(const short* __restrict__ qkvb,
                                                  const short* __restrict__ vbT,
                                                  short* __restrict__ yb,
                                                  short* __restrict__ Opart,
                                                  float* __restrict__ Lpart) {
    __shared__ alignas(16) short Kt[2][64 * 64];      // [k][d], XOR-swizzled rows
    __shared__ alignas(16) short Vt[2][64 * 64];      // [d][k], XOR-swizzled rows
    __shared__ alignas(16) short Ps[4][16][72];       // wave-private P[q][k]

    int b = blockIdx.x;
    int h, qt, t0, t1, mode;                          // mode: 0 direct, 1 kh0 partial, 2 kh1 partial
    if (b < 256)      { h = b & 15; qt = 16 + (b >> 4); t0 = 0;  t1 = 16; mode = 1; }
    else if (b < 512) { int c = b - 256; h = c & 15; qt = 31 - (c >> 4); t0 = 17; t1 = qt; mode = 2; }
    else              { int c = b - 512; h = c & 15; qt = c >> 4; t0 = 0; t1 = qt; mode = 0; }
    int nt = t1 - t0 + 1;                             // may be 0 (mode 2, qt==16)

    int tid = threadIdx.x;
    int w = tid >> 6, l = tid & 63;
    int lq = l & 15, g = l >> 4;
    int qrl = w * 16 + lq;                            // q-row local to the 64-row q-tile
    int qrow = qt * 64 + qrl;

    const short* qbase = qkvb + (size_t)qrow * N3 + h * 64;
    bf16x8 qf0 = *(const bf16x8*)(qbase + g * 8);
    bf16x8 qf1 = *(const bf16x8*)(qbase + 32 + g * 8);

    f32x4 accO[4] = {};    // [f]: d = 16f + lq ; q-rows = 4g + r
    float lsum = 0.0f;

    // staging geometry: thread covers rows srow, srow+32; 8 cols at scol
    int srow = tid >> 3, scol = (tid & 7) * 8;
    const short* kgb = qkvb + C + h * 64 + scol;
    const short* vgb = vbT + (size_t)(h * 64) * T + scol;
    int wb0 = srow * 128 + ((scol * 2) ^ ((srow & 7) << 4));
    int wb1 = (srow + 32) * 128 + ((scol * 2) ^ ((srow & 7) << 4));

    uint4 kr0, kr1, vr0, vr1;
    auto stageRegs = [&](int tile) {
        int kb = tile * 64;
        kr0 = *(const uint4*)(kgb + (size_t)(kb + srow) * N3);
        kr1 = *(const uint4*)(kgb + (size_t)(kb + srow + 32) * N3);
        vr0 = *(const uint4*)(vgb + (size_t)srow * T + kb);
        vr1 = *(const uint4*)(vgb + (size_t)(srow + 32) * T + kb);
    };
    auto writeLds = [&](int buf) {
        *(uint4*)((char*)Kt[buf] + wb0) = kr0;
        *(uint4*)((char*)Kt[buf] + wb1) = kr1;
        *(uint4*)((char*)Vt[buf] + wb0) = vr0;
        *(uint4*)((char*)Vt[buf] + wb1) = vr1;
    };

    auto do_tile = [&](int buf, bool masked) {
        const char* Kc = (const char*)Kt[buf];
        const char* Vc = (const char*)Vt[buf];
        // ---- S^T = K · Q^T ----
        f32x4 s[4] = {};
        __builtin_amdgcn_s_setprio(1);
        #pragma unroll
        for (int f = 0; f < 4; ++f) {
            int row = f * 16 + lq;
            const char* kr_ = Kc + row * 128;
            int sw = (row & 7) << 4;
            bf16x8 a0 = *(const bf16x8*)(kr_ + ((g * 16) ^ sw));
            bf16x8 a1 = *(const bf16x8*)(kr_ + ((64 + g * 16) ^ sw));
            s[f] = MFMA16(a0, qf0, s[f]);
            s[f] = MFMA16(a1, qf1, s[f]);
        }
        __builtin_amdgcn_s_setprio(0);
        // ---- streaming softmax: p = exp(s/8), no max-tracking ----
        float p[16];
        #pragma unroll
        for (int f = 0; f < 4; ++f)
            #pragma unroll
            for (int r = 0; r < 4; ++r) {
                float sv = s[f][r] * 0.125f;
                if (masked) {
                    int kl = f * 16 + g * 4 + r;
                    sv = (kl > qrl) ? -INFINITY : sv;
                }
                float pv = __expf(sv);
                p[f * 4 + r] = pv;
                lsum += pv;
            }
        // ---- pack P to bf16, transpose through wave-private LDS ----
        #pragma unroll
        for (int f = 0; f < 4; ++f) {
            unsigned u0, u1;
            asm("v_cvt_pk_bf16_f32 %0, %1, %2" : "=v"(u0) : "v"(p[f * 4 + 0]), "v"(p[f * 4 + 1]));
            asm("v_cvt_pk_bf16_f32 %0, %1, %2" : "=v"(u1) : "v"(p[f * 4 + 2]), "v"(p[f * 4 + 3]));
            uint2 uu; uu.x = u0; uu.y = u1;
            *(uint2*)&Ps[w][lq][f * 16 + g * 4] = uu;
        }
        // ---- O += P · V ----
        __builtin_amdgcn_s_setprio(1);
        #pragma unroll
        for (int kh = 0; kh < 2; ++kh) {
            bf16x8 pa = *(const bf16x8*)&Ps[w][lq][kh * 32 + g * 8];
            #pragma unroll
            for (int f = 0; f < 4; ++f) {
                int vrow = f * 16 + lq;
                const char* vr_ = Vc + vrow * 128;
                bf16x8 vb = *(const bf16x8*)(vr_ + (((kh * 32 + g * 8) * 2) ^ ((vrow & 7) << 4)));
                accO[f] = MFMA16(pa, vb, accO[f]);
            }
        }
        __builtin_amdgcn_s_setprio(0);
    };

    // prologue: stage first tile (if any work)
    if (nt > 0) { stageRegs(t0); writeLds(0); }
    __syncthreads();

    for (int j = 0; j < nt; ++j) {
        int t = t0 + j;
        bool pf = (j + 1 < nt);
        if (pf) stageRegs(t + 1);
        do_tile(j & 1, t == qt);
        if (pf) writeLds((j & 1) ^ 1);
        __syncthreads();
    }

    // row-sum reduce across the 4 g-groups (result replicated per lane)
    lsum += __shfl_xor(lsum, 16);
    lsum += __shfl_xor(lsum, 32);

    if (mode == 0) {
        float linv_own = 1.0f / lsum;
        float li[4];
        #pragma unroll
        for (int r = 0; r < 4; ++r) li[r] = __shfl(linv_own, g * 4 + r);
        #pragma unroll
        for (int f = 0; f < 4; ++f)
            #pragma unroll
            for (int r = 0; r < 4; ++r) {
                int trow = qt * 64 + w * 16 + g * 4 + r;
                yb[(size_t)trow * C + h * 64 + f * 16 + lq] = f2bf(accO[f][r] * li[r]);
            }
    } else {
        int kh = mode - 1;
        int slab = h * 16 + (qt - 16);
        short* Ob = Opart + ((size_t)kh * 256 + slab) * 4096;
        #pragma unroll
        for (int f = 0; f < 4; ++f)
            #pragma unroll
            for (int r = 0; r < 4; ++r)
                Ob[(w * 16 + g * 4 + r) * 64 + f * 16 + lq] = f2bf(accO[f][r]);
        if (g == 0) Lpart[((size_t)kh * 256 + slab) * 64 + w * 16 + lq] = lsum;
    }
}

// ---------------- combine: sum kh0+kh1 bf16 partials, normalize, write yb (qt>=16 rows) ----------------
__global__ __launch_bounds__(256) void attn_combine(const short* __restrict__ Opart,
                                                    const float* __restrict__ Lpart,
                                                    short* __restrict__ yb) {
    __shared__ float linvS[64];
    int s = blockIdx.x;                   // slab = h*16 + (qt-16)
    int h = s >> 4, qt = 16 + (s & 15);
    int tid = threadIdx.x;
    if (tid < 64)
        linvS[tid] = 1.0f / (Lpart[(size_t)s * 64 + tid] + Lpart[(size_t)(256 + s) * 64 + tid]);
    __syncthreads();
    const short* O0 = Opart + (size_t)s * 4096;
    const short* O1 = Opart + (size_t)(256 + s) * 4096;
    #pragma unroll
    for (int e = 0; e < 2; ++e) {
        int base = tid * 8 + e * 2048;    // 8 consecutive d within one q row
        bf16x8 a = *(const bf16x8*)(O0 + base);
        bf16x8 c = *(const bf16x8*)(O1 + base);
        int q = base >> 6, d = base & 63;
        float li = linvS[q];
        bf16x8 o;
        #pragma unroll
        for (int i = 0; i < 8; ++i) o[i] = f2bf((bf2f(a[i]) + bf2f(c[i])) * li);
        *(bf16x8*)(yb + (size_t)(qt * 64 + q) * C + h * 64 + d) = o;
    }
}

extern "C" void kernel_launch(void* const* d_in, const int* in_sizes, int n_in,
                              void* d_out, int out_size, void* d_ws, size_t ws_size,
                              hipStream_t stream) {
    const float* x       = (const float*)d_in[0];
    const float* cumsc   = (const float*)d_in[1];
    const float* padmask = (const float*)d_in[2];
    const int*   tok     = (const int*)d_in[3];
    const float* w_attn  = (const float*)d_in[4];
    const float* b_attn  = (const float*)d_in[5];
    const float* w_proj  = (const float*)d_in[6];
    const float* b_proj  = (const float*)d_in[7];
    float* out = (float*)d_out;

    float* part   = (float*)d_ws;                 // 2048
    float* pm_tok = part + 2048;                  // 2048
    float* Lpart  = pm_tok + 2048;                // 2*256*64
    short* Opart  = (short*)(Lpart + 2 * 256 * 64);  // 2*256*4096 bf16 (4MB)
    short* xb     = Opart + (size_t)2 * 256 * 4096;  // T*C
    short* wabT   = xb + (size_t)T * C;           // 3C*C
    short* wpbT   = wabT + (size_t)N3 * C;        // C*C
    short* qkvb   = wpbT + (size_t)C * C;         // T*3C (v-section unused)
    short* vbT    = qkvb + (size_t)T * N3;        // C*T
    short* yb     = vbT + (size_t)C * T;          // T*C

    pre_kernel<<<3073, 256, 0, stream>>>(x, w_attn, w_proj, tok, padmask,
                                         xb, wabT, wpbT, part, pm_tok);
    gemm_bt64<1, 1><<<dim3(N3 / 128, T / 64), 256, 0, stream>>>(
        xb, wabT, b_attn, qkvb, T, N3, C, part, cumsc, pm_tok, vbT);
    attn_flash<<<768, 256, 0, stream>>>(qkvb, vbT, yb, Opart, Lpart);
    attn_combine<<<256, 256, 0, stream>>>(Opart, Lpart, yb);
    gemm_bt64<0, 0><<<dim3(C / 128, T / 64), 256, 0, stream>>>(
        yb, wpbT, b_proj, out, T, C, C, nullptr, nullptr, nullptr, nullptr);
}